// Round 5
// baseline (154.090 us; speedup 1.0000x reference)
//
#include <hip/hip_runtime.h>
#include <hip/hip_bf16.h>

#define N_OBJ   32
#define G_TOTAL 4960      // C(32,3)
#define GPAD    5120      // K padded for clean split-K
#define N_FILT  16
#define REL_D   16
#define BATCH   32
#define NQ      512
#define ZSPLIT  8
#define KCH     640       // GPAD / ZSPLIT
#define NIT     20        // KCH / 32

typedef __attribute__((ext_vector_type(8))) short bf16x8;
typedef __attribute__((ext_vector_type(4))) float f32x4;

static __device__ inline unsigned short f2bf(float x) {
    union { float f; unsigned int u; } v; v.f = x;
    unsigned int r = v.u + 0x7fffu + ((v.u >> 16) & 1u);   // RNE
    return (unsigned short)(r >> 16);
}
static __device__ inline float bfbits2f(unsigned int bits) {
    union { unsigned int u; float f; } v; v.u = bits; return v.f;
}
static __device__ inline void gload_lds16(const void* g, void* l) {
    __builtin_amdgcn_global_load_lds(
        (const __attribute__((address_space(1))) unsigned int*)g,
        (__attribute__((address_space(3))) unsigned int*)(unsigned int)(uintptr_t)l,
        16, 0, 0);
}
// unrank lexicographic 3-combination of 32
static __device__ inline void unrank3(int g, int& a, int& b, int& c) {
    int rem = g;
    for (a = 0; a < 30; a++) { int cnt = ((31 - a) * (30 - a)) >> 1; if (rem < cnt) break; rem -= cnt; }
    for (b = a + 1; b < 31; b++) { if (rem < 31 - b) break; rem -= 31 - b; }
    c = b + 1 + rem;
}

// ================= L1: normw (blocks 0..511) + pairconv (512..1663) ==============
__global__ __launch_bounds__(256) void k_front(const float* __restrict__ logits,
                                               const float* __restrict__ inputs,
                                               const float* __restrict__ filters,
                                               unsigned short* __restrict__ normw,
                                               unsigned short* __restrict__ D) {
    __shared__ __align__(16) char smem[11648];
    int t = threadIdx.x;
    int role = blockIdx.x;

    if (role < NQ) {
        // ---------- normw: softplus -> triple product -> softmax -> bf16, K-padded --
        float* sp  = (float*)smem;                            // 32 floats
        float* red = (float*)(smem + 128);                    // 4 floats
        unsigned short* wrow = (unsigned short*)(smem + 144); // 5120 u16
        int q = role;
        if (t < N_OBJ) {
            float x = logits[q * N_OBJ + t];
            sp[t] = (x > 15.f) ? x : log1pf(expf(x));
        }
        if (t < GPAD - G_TOTAL) wrow[G_TOTAL + t] = 0;        // zero the K-pad
        __syncthreads();

        int g0 = t * 20;
        int aa, bb, cc;
        unrank3(g0, aa, bb, cc);

        float w[20];
        float lmax = -1e30f;
#pragma unroll
        for (int k = 0; k < 20; k++) {
            float v = -1e30f;
            if (g0 + k < G_TOTAL) v = sp[aa] * sp[bb] * sp[cc];
            w[k] = v;
            lmax = fmaxf(lmax, v);
            cc++;
            if (cc >= 32) { bb++; cc = bb + 1; if (cc >= 32) { aa++; bb = aa + 1; cc = bb + 1; } }
        }
#pragma unroll
        for (int off = 32; off; off >>= 1) lmax = fmaxf(lmax, __shfl_down(lmax, off, 64));
        if ((t & 63) == 0) red[t >> 6] = lmax;
        __syncthreads();
        float wmax = fmaxf(fmaxf(red[0], red[1]), fmaxf(red[2], red[3]));

        float lsum = 0.f;
#pragma unroll
        for (int k = 0; k < 20; k++) {
            float e = (g0 + k < G_TOTAL) ? expf(w[k] - wmax) : 0.f;
            w[k] = e;
            lsum += e;
        }
#pragma unroll
        for (int off = 32; off; off >>= 1) lsum += __shfl_down(lsum, off, 64);
        __syncthreads();
        if ((t & 63) == 0) red[t >> 6] = lsum;
        __syncthreads();
        float inv = 1.f / (red[0] + red[1] + red[2] + red[3]);

#pragma unroll
        for (int k = 0; k < 20; k++)
            if (g0 + k < G_TOTAL) wrow[g0 + k] = f2bf(w[k] * inv);
        __syncthreads();
        // coalesced padded row write: 5120 u16 = 640 uint4
        uint4* dstrow = (uint4*)(normw + (size_t)q * GPAD);
        const uint4* srow = (const uint4*)wrow;
        for (int i = t; i < 640; i += 256) dstrow[i] = srow[i];
    } else {
        // ---------- pairconv: D[xy][p][b*16+f] = dot_d(inputs[b,x,y,:], filters[f,p,:])
        float* flt = (float*)smem;            // [f][p_pad] 16*180 floats
        int bid = role - NQ;                  // 0..1151
        int p = bid >> 7;                     // 0..8
        int xb = bid & 127;
        for (int i = t; i < 576; i += 256) {
            int i4 = i * 4;
            int f = i4 / 144;
            int r = i4 - f * 144;
            *(float4*)&flt[f * 180 + (r >> 4) * 20 + (r & 15)] = *(const float4*)(filters + i4);
        }
        __syncthreads();

        int row = xb * 256 + t;               // b*1024 + xy
        int b = row >> 10, xy = row & 1023;
        const float4* src = (const float4*)(inputs + (size_t)row * 16);
        float4 s0 = src[0], s1 = src[1], s2 = src[2], s3 = src[3];

        unsigned short outv[16];
        const float* fb = &flt[p * 20];
#pragma unroll
        for (int f = 0; f < 16; f++) {
            float4 f0 = *(const float4*)(fb + f * 180);
            float4 f1 = *(const float4*)(fb + f * 180 + 4);
            float4 f2 = *(const float4*)(fb + f * 180 + 8);
            float4 f3 = *(const float4*)(fb + f * 180 + 12);
            float d = s0.x * f0.x + s0.y * f0.y + s0.z * f0.z + s0.w * f0.w;
            d += s1.x * f1.x + s1.y * f1.y + s1.z * f1.z + s1.w * f1.w;
            d += s2.x * f2.x + s2.y * f2.y + s2.z * f2.z + s2.w * f2.w;
            d += s3.x * f3.x + s3.y * f3.y + s3.z * f3.z + s3.w * f3.w;
            outv[f] = f2bf(d);
        }
        uint4* dst = (uint4*)(D + ((size_t)(xy * 9 + p)) * 512 + b * 16);
        dst[0] = ((uint4*)outv)[0];
        dst[1] = ((uint4*)outv)[1];
    }
}

// ===== L2: gather 9 pairs -> relT[n][g] (blocks 0..619) + zero cnt (block 620) ====
__global__ __launch_bounds__(256) void k_mid(const unsigned short* __restrict__ D,
                                             unsigned short* __restrict__ relT,
                                             int* __restrict__ cnt) {
    __shared__ int tri[8];
    int t = threadIdx.x;
    int role = blockIdx.x;
    if (role >= 620) {
        if (t < 64) cnt[t] = 0;
        return;
    }
    int g0 = role * 8;
    if (t < 8) {
        int a, b, c;
        unrank3(g0 + t, a, b, c);
        tri[t] = a | (b << 8) | (c << 16);
    }
    __syncthreads();

    float s0[8], s1[8];
#pragma unroll
    for (int g = 0; g < 8; g++) {
        int pk = tri[g];
        int xs[3] = { pk & 255, (pk >> 8) & 255, (pk >> 16) & 255 };
        float x0 = 0.f, x1 = 0.f;
#pragma unroll
        for (int i = 0; i < 3; i++)
#pragma unroll
            for (int j = 0; j < 3; j++) {
                int xy = xs[i] * 32 + xs[j];
                unsigned int v = *(const unsigned int*)(D + (size_t)(xy * 9 + i * 3 + j) * 512 + t * 2);
                x0 += bfbits2f(v << 16);
                x1 += bfbits2f(v & 0xffff0000u);
            }
        s0[g] = x0; s1[g] = x1;
    }
    unsigned int pack0[4], pack1[4];
#pragma unroll
    for (int k = 0; k < 4; k++) {
        pack0[k] = f2bf(s0[2 * k]) | ((unsigned int)f2bf(s0[2 * k + 1]) << 16);
        pack1[k] = f2bf(s1[2 * k]) | ((unsigned int)f2bf(s1[2 * k + 1]) << 16);
    }
    *(uint4*)(relT + (size_t)(2 * t) * GPAD + g0)     = *(uint4*)pack0;
    *(uint4*)(relT + (size_t)(2 * t + 1) * GPAD + g0) = *(uint4*)pack1;
}

// ====== L3: split-K GEMM + last-block fixup reduce (no extra kernel, no spin) =====
__global__ __launch_bounds__(256) void k_gemmred(const unsigned short* __restrict__ A,
                                                 const unsigned short* __restrict__ Bm,
                                                 float* __restrict__ part,
                                                 int* __restrict__ cnt,
                                                 float* __restrict__ out) {
    __shared__ __align__(16) unsigned short As[2][64 * 32];
    __shared__ __align__(16) unsigned short Bs[2][64 * 32];
    __shared__ int isfix;
    int tid = threadIdx.x;
    int q0 = blockIdx.x * 64, n0 = blockIdx.y * 64, z = blockIdx.z;
    int k0 = z * KCH;
    int wave = tid >> 6, lane = tid & 63;
    int wm = wave & 1, wn = wave >> 1;
    int row16 = lane & 15, quad = lane >> 4;

    int srow = tid >> 2;
    int schunk = (tid & 3) ^ ((srow >> 1) & 3);
    const unsigned short* ga = A + (size_t)(q0 + srow) * GPAD + k0 + schunk * 8;
    const unsigned short* gb = Bm + (size_t)(n0 + srow) * GPAD + k0 + schunk * 8;
    char* lA = (char*)&As[0][0] + tid * 16;
    char* lB = (char*)&Bs[0][0] + tid * 16;

    f32x4 acc[2][2] = {};
    int fchunk = (quad ^ ((row16 >> 1) & 3)) * 8;

    gload_lds16(ga, lA);
    gload_lds16(gb, lB);
    for (int it = 0; it < NIT; ++it) {
        __syncthreads();
        if (it + 1 < NIT) {
            int nb = (it + 1) & 1;
            gload_lds16(ga + (it + 1) * 32, lA + nb * 64 * 32 * 2);
            gload_lds16(gb + (it + 1) * 32, lB + nb * 64 * 32 * 2);
        }
        int buf = it & 1;
        bf16x8 afr[2], bfr[2];
#pragma unroll
        for (int mi = 0; mi < 2; mi++)
            afr[mi] = *(const bf16x8*)&As[buf][(wm * 32 + mi * 16 + row16) * 32 + fchunk];
#pragma unroll
        for (int ni = 0; ni < 2; ni++)
            bfr[ni] = *(const bf16x8*)&Bs[buf][(wn * 32 + ni * 16 + row16) * 32 + fchunk];
#pragma unroll
        for (int mi = 0; mi < 2; mi++)
#pragma unroll
            for (int ni = 0; ni < 2; ni++)
                acc[mi][ni] = __builtin_amdgcn_mfma_f32_16x16x32_bf16(
                    afr[mi], bfr[ni], acc[mi][ni], 0, 0, 0);
    }

    // write f32 partial for this z
    float* pz = part + (size_t)z * (NQ * 512);
#pragma unroll
    for (int mi = 0; mi < 2; mi++)
#pragma unroll
        for (int ni = 0; ni < 2; ni++)
#pragma unroll
            for (int r = 0; r < 4; r++) {
                int q = q0 + wm * 32 + mi * 16 + quad * 4 + r;
                int n = n0 + wn * 32 + ni * 16 + row16;
                pz[q * 512 + n] = acc[mi][ni][r];
            }

    // make partial visible device-wide, then count in
    __threadfence();
    __syncthreads();
    if (tid == 0) {
        int old = atomicAdd(&cnt[blockIdx.x * 8 + blockIdx.y], 1);
        isfix = (old == ZSPLIT - 1);
    }
    __syncthreads();
    if (!isfix) return;

    // fixup: this block saw all ZSPLIT partials complete -> reduce + write out
    int n = tid & 63;
    int qrow = tid >> 6;                      // 0..3
#pragma unroll
    for (int pass = 0; pass < 16; pass++) {
        int q = q0 + pass * 4 + qrow;
        float s = 0.f;
#pragma unroll
        for (int zz = 0; zz < ZSPLIT; zz++)
            s += __hip_atomic_load(part + (size_t)zz * (NQ * 512) + q * 512 + n0 + n,
                                   __ATOMIC_RELAXED, __HIP_MEMORY_SCOPE_AGENT);
        int nn = n0 + n;
        out[(size_t)(nn >> 4) * (NQ * REL_D) + q * 16 + (nn & 15)] = s;
    }
}

extern "C" void kernel_launch(void* const* d_in, const int* in_sizes, int n_in,
                              void* d_out, int out_size, void* d_ws, size_t ws_size,
                              hipStream_t stream) {
    const float* inputs  = (const float*)d_in[0];   // (32,32,32,16)
    const float* logits  = (const float*)d_in[1];   // (512,32)
    const float* filters = (const float*)d_in[2];   // (16,3,3,16)
    float* out = (float*)d_out;                     // (32,512,16)

    char* ws = (char*)d_ws;
    unsigned short* normw = (unsigned short*)ws;                 //  5,242,880 B
    unsigned short* D     = (unsigned short*)(ws + 5242880);     //  9,437,184 B
    unsigned short* relT  = (unsigned short*)(ws + 14680064);    //  5,242,880 B
    float*          part  = (float*)(ws + 19922944);             //  8,388,608 B
    int*            cnt   = (int*)(ws + 28311552);               //  256 B

    k_front<<<NQ + 1152, 256, 0, stream>>>(logits, inputs, filters, normw, D);
    k_mid<<<621, 256, 0, stream>>>(D, relT, cnt);
    k_gemmred<<<dim3(8, 8, ZSPLIT), 256, 0, stream>>>(normw, relT, part, cnt, out);
}

// Round 6
// 97.618 us; speedup vs baseline: 1.5785x; 1.5785x over previous
//
#include <hip/hip_runtime.h>
#include <hip/hip_bf16.h>

#define N_OBJ   32
#define G_TOTAL 4960      // C(32,3)
#define GPAD    5120      // K padded: 4 waves x 40 iters x 32
#define N_FILT  16
#define REL_D   16
#define BATCH   32
#define NQ      512
#define KWAVE   1280      // GPAD / 4 waves
#define NIT     40        // KWAVE / 32

typedef __attribute__((ext_vector_type(8))) short bf16x8;
typedef __attribute__((ext_vector_type(4))) float f32x4;

static __device__ inline unsigned short f2bf(float x) {
    union { float f; unsigned int u; } v; v.f = x;
    unsigned int r = v.u + 0x7fffu + ((v.u >> 16) & 1u);   // RNE
    return (unsigned short)(r >> 16);
}
static __device__ inline float bfbits2f(unsigned int bits) {
    union { unsigned int u; float f; } v; v.u = bits; return v.f;
}
static __device__ inline void gload_lds16(const void* g, void* l) {
    __builtin_amdgcn_global_load_lds(
        (const __attribute__((address_space(1))) unsigned int*)g,
        (__attribute__((address_space(3))) unsigned int*)(unsigned int)(uintptr_t)l,
        16, 0, 0);
}
// unrank lexicographic 3-combination of 32
static __device__ inline void unrank3(int g, int& a, int& b, int& c) {
    int rem = g;
    for (a = 0; a < 30; a++) { int cnt = ((31 - a) * (30 - a)) >> 1; if (rem < cnt) break; rem -= cnt; }
    for (b = a + 1; b < 31; b++) { if (rem < 31 - b) break; rem -= 31 - b; }
    c = b + 1 + rem;
}

// ================= L1: normw (blocks 0..511) + pairconv (512..1663) ==============
__global__ __launch_bounds__(256) void k_front(const float* __restrict__ logits,
                                               const float* __restrict__ inputs,
                                               const float* __restrict__ filters,
                                               unsigned short* __restrict__ normw,
                                               unsigned short* __restrict__ D) {
    __shared__ __align__(16) char smem[11648];
    int t = threadIdx.x;
    int role = blockIdx.x;

    if (role < NQ) {
        // ---------- normw: softplus -> triple product -> softmax -> bf16, K-padded --
        float* sp  = (float*)smem;                            // 32 floats
        float* red = (float*)(smem + 128);                    // 4 floats
        unsigned short* wrow = (unsigned short*)(smem + 144); // 5120 u16
        int q = role;
        if (t < N_OBJ) {
            float x = logits[q * N_OBJ + t];
            sp[t] = (x > 15.f) ? x : log1pf(expf(x));
        }
        if (t < GPAD - G_TOTAL) wrow[G_TOTAL + t] = 0;        // zero the K-pad
        __syncthreads();

        int g0 = t * 20;
        int aa, bb, cc;
        unrank3(g0, aa, bb, cc);

        float w[20];
        float lmax = -1e30f;
#pragma unroll
        for (int k = 0; k < 20; k++) {
            float v = -1e30f;
            if (g0 + k < G_TOTAL) v = sp[aa] * sp[bb] * sp[cc];
            w[k] = v;
            lmax = fmaxf(lmax, v);
            cc++;
            if (cc >= 32) { bb++; cc = bb + 1; if (cc >= 32) { aa++; bb = aa + 1; cc = bb + 1; } }
        }
#pragma unroll
        for (int off = 32; off; off >>= 1) lmax = fmaxf(lmax, __shfl_down(lmax, off, 64));
        if ((t & 63) == 0) red[t >> 6] = lmax;
        __syncthreads();
        float wmax = fmaxf(fmaxf(red[0], red[1]), fmaxf(red[2], red[3]));

        float lsum = 0.f;
#pragma unroll
        for (int k = 0; k < 20; k++) {
            float e = (g0 + k < G_TOTAL) ? expf(w[k] - wmax) : 0.f;
            w[k] = e;
            lsum += e;
        }
#pragma unroll
        for (int off = 32; off; off >>= 1) lsum += __shfl_down(lsum, off, 64);
        __syncthreads();
        if ((t & 63) == 0) red[t >> 6] = lsum;
        __syncthreads();
        float inv = 1.f / (red[0] + red[1] + red[2] + red[3]);

#pragma unroll
        for (int k = 0; k < 20; k++)
            if (g0 + k < G_TOTAL) wrow[g0 + k] = f2bf(w[k] * inv);
        __syncthreads();
        // coalesced padded row write: 5120 u16 = 640 uint4
        uint4* dstrow = (uint4*)(normw + (size_t)q * GPAD);
        const uint4* srow = (const uint4*)wrow;
        for (int i = t; i < 640; i += 256) dstrow[i] = srow[i];
    } else {
        // ---------- pairconv: D[xy][p][b*16+f] = dot_d(inputs[b,x,y,:], filters[f,p,:])
        float* flt = (float*)smem;            // [f][p_pad] 16*180 floats
        int bid = role - NQ;                  // 0..1151
        int p = bid >> 7;                     // 0..8
        int xb = bid & 127;
        for (int i = t; i < 576; i += 256) {
            int i4 = i * 4;
            int f = i4 / 144;
            int r = i4 - f * 144;
            *(float4*)&flt[f * 180 + (r >> 4) * 20 + (r & 15)] = *(const float4*)(filters + i4);
        }
        __syncthreads();

        int row = xb * 256 + t;               // b*1024 + xy
        int b = row >> 10, xy = row & 1023;
        const float4* src = (const float4*)(inputs + (size_t)row * 16);
        float4 s0 = src[0], s1 = src[1], s2 = src[2], s3 = src[3];

        unsigned short outv[16];
        const float* fb = &flt[p * 20];
#pragma unroll
        for (int f = 0; f < 16; f++) {
            float4 f0 = *(const float4*)(fb + f * 180);
            float4 f1 = *(const float4*)(fb + f * 180 + 4);
            float4 f2 = *(const float4*)(fb + f * 180 + 8);
            float4 f3 = *(const float4*)(fb + f * 180 + 12);
            float d = s0.x * f0.x + s0.y * f0.y + s0.z * f0.z + s0.w * f0.w;
            d += s1.x * f1.x + s1.y * f1.y + s1.z * f1.z + s1.w * f1.w;
            d += s2.x * f2.x + s2.y * f2.y + s2.z * f2.z + s2.w * f2.w;
            d += s3.x * f3.x + s3.y * f3.y + s3.z * f3.z + s3.w * f3.w;
            outv[f] = f2bf(d);
        }
        uint4* dst = (uint4*)(D + ((size_t)(xy * 9 + p)) * 512 + b * 16);
        dst[0] = ((uint4*)outv)[0];
        dst[1] = ((uint4*)outv)[1];
    }
}

// ===== L2: gather 9 pairs -> relT[n][g]  (620 blocks, 8 g each) ===================
__global__ __launch_bounds__(256) void k_mid(const unsigned short* __restrict__ D,
                                             unsigned short* __restrict__ relT) {
    __shared__ int tri[8];
    int t = threadIdx.x;
    int g0 = blockIdx.x * 8;
    if (t < 8) {
        int a, b, c;
        unrank3(g0 + t, a, b, c);
        tri[t] = a | (b << 8) | (c << 16);
    }
    __syncthreads();

    float s0[8], s1[8];
#pragma unroll
    for (int g = 0; g < 8; g++) {
        int pk = tri[g];
        int xs[3] = { pk & 255, (pk >> 8) & 255, (pk >> 16) & 255 };
        float x0 = 0.f, x1 = 0.f;
#pragma unroll
        for (int i = 0; i < 3; i++)
#pragma unroll
            for (int j = 0; j < 3; j++) {
                int xy = xs[i] * 32 + xs[j];
                unsigned int v = *(const unsigned int*)(D + (size_t)(xy * 9 + i * 3 + j) * 512 + t * 2);
                x0 += bfbits2f(v << 16);
                x1 += bfbits2f(v & 0xffff0000u);
            }
        s0[g] = x0; s1[g] = x1;
    }
    unsigned int pack0[4], pack1[4];
#pragma unroll
    for (int k = 0; k < 4; k++) {
        pack0[k] = f2bf(s0[2 * k]) | ((unsigned int)f2bf(s0[2 * k + 1]) << 16);
        pack1[k] = f2bf(s1[2 * k]) | ((unsigned int)f2bf(s1[2 * k + 1]) << 16);
    }
    *(uint4*)(relT + (size_t)(2 * t) * GPAD + g0)     = *(uint4*)pack0;
    *(uint4*)(relT + (size_t)(2 * t + 1) * GPAD + g0) = *(uint4*)pack1;
}

// ====== L3: full-K GEMM, 32x32 tile/block, K split across 4 waves, no barriers ====
// in K-loop. Per-wave private double-buffered LDS; s_waitcnt-only pipelining.
__global__ __launch_bounds__(256) void k_gemmf(const unsigned short* __restrict__ A,
                                               const unsigned short* __restrict__ Bm,
                                               float* __restrict__ out) {
    __shared__ __align__(16) char smem[32768];   // [wave][buf][A(2KB)|B(2KB)]
    int tid = threadIdx.x;
    int wave = tid >> 6, lane = tid & 63;
    int q0 = blockIdx.x * 32, n0 = blockIdx.y * 32;
    int row16 = lane & 15, quad = lane >> 4;

    // staging map: lane -> (srow = lane>>2 in 0..15, chunk slot lane&3), XOR swizzle
    int srow = lane >> 2;
    int schunk = (lane & 3) ^ ((srow >> 1) & 3);
    const unsigned short* gA = A  + (size_t)(q0 + srow) * GPAD + wave * KWAVE + schunk * 8;
    const unsigned short* gB = Bm + (size_t)(n0 + srow) * GPAD + wave * KWAVE + schunk * 8;
    char* lw = smem + wave * 8192;
    char* ld = lw + lane * 16;

    f32x4 acc[2][2] = {};
    int fslot = (quad ^ ((row16 >> 1) & 3)) * 16;

    // preload buf 0
    gload_lds16(gA,             ld);
    gload_lds16(gA + 16 * GPAD, ld + 1024);
    gload_lds16(gB,             ld + 2048);
    gload_lds16(gB + 16 * GPAD, ld + 3072);

#pragma unroll 2
    for (int it = 0; it < NIT; ++it) {
        int buf = it & 1;
        asm volatile("s_waitcnt vmcnt(0)" ::: "memory");   // current buf landed
        const char* fb = lw + buf * 4096;
        bf16x8 a0 = *(const bf16x8*)(fb + row16 * 64 + fslot);
        bf16x8 a1 = *(const bf16x8*)(fb + 1024 + row16 * 64 + fslot);
        bf16x8 b0 = *(const bf16x8*)(fb + 2048 + row16 * 64 + fslot);
        bf16x8 b1 = *(const bf16x8*)(fb + 3072 + row16 * 64 + fslot);
        asm volatile("s_waitcnt lgkmcnt(0)" ::: "memory"); // frags in regs
        if (it + 1 < NIT) {                                // prefetch other buf
            int ko = (it + 1) * 32;
            char* ln = ld + (buf ^ 1) * 4096;
            gload_lds16(gA + ko,             ln);
            gload_lds16(gA + 16 * GPAD + ko, ln + 1024);
            gload_lds16(gB + ko,             ln + 2048);
            gload_lds16(gB + 16 * GPAD + ko, ln + 3072);
        }
        acc[0][0] = __builtin_amdgcn_mfma_f32_16x16x32_bf16(a0, b0, acc[0][0], 0, 0, 0);
        acc[0][1] = __builtin_amdgcn_mfma_f32_16x16x32_bf16(a0, b1, acc[0][1], 0, 0, 0);
        acc[1][0] = __builtin_amdgcn_mfma_f32_16x16x32_bf16(a1, b0, acc[1][0], 0, 0, 0);
        acc[1][1] = __builtin_amdgcn_mfma_f32_16x16x32_bf16(a1, b1, acc[1][1], 0, 0, 0);
    }

    // cross-wave K-reduction through LDS (reuse staging space)
    __syncthreads();
    float* red = (float*)smem;                 // 4 waves x 1024 f32 = 16 KB
#pragma unroll
    for (int mi = 0; mi < 2; mi++)
#pragma unroll
        for (int ni = 0; ni < 2; ni++)
#pragma unroll
            for (int r = 0; r < 4; r++)
                red[wave * 1024 + (mi * 16 + quad * 4 + r) * 32 + ni * 16 + row16] =
                    acc[mi][ni][r];
    __syncthreads();

    int e = tid * 4;                            // 4 consecutive elems per thread
    float4 s = *(const float4*)&red[e];
#pragma unroll
    for (int w = 1; w < 4; w++) {
        float4 v = *(const float4*)&red[w * 1024 + e];
        s.x += v.x; s.y += v.y; s.z += v.z; s.w += v.w;
    }
    int ql = e >> 5, nl = e & 31;
    int nn = n0 + nl;
    *(float4*)(out + (size_t)(nn >> 4) * (NQ * REL_D) + (q0 + ql) * 16 + (nn & 15)) = s;
}

extern "C" void kernel_launch(void* const* d_in, const int* in_sizes, int n_in,
                              void* d_out, int out_size, void* d_ws, size_t ws_size,
                              hipStream_t stream) {
    const float* inputs  = (const float*)d_in[0];   // (32,32,32,16)
    const float* logits  = (const float*)d_in[1];   // (512,32)
    const float* filters = (const float*)d_in[2];   // (16,3,3,16)
    float* out = (float*)d_out;                     // (32,512,16)

    char* ws = (char*)d_ws;
    unsigned short* normw = (unsigned short*)ws;                 //  5,242,880 B
    unsigned short* D     = (unsigned short*)(ws + 5242880);     //  9,437,184 B
    unsigned short* relT  = (unsigned short*)(ws + 14680064);    //  5,242,880 B

    k_front<<<NQ + 1152, 256, 0, stream>>>(logits, inputs, filters, normw, D);
    k_mid<<<G_TOTAL / 8, 256, 0, stream>>>(D, relT);
    k_gemmf<<<dim3(16, 16), 256, 0, stream>>>(normw, relT, out);
}

// Round 8
// 96.939 us; speedup vs baseline: 1.5896x; 1.0070x over previous
//
#include <hip/hip_runtime.h>
#include <hip/hip_bf16.h>

#define N_OBJ   32
#define G_TOTAL 4960      // C(32,3)
#define GPAD    5120      // K padded: 4 waves x 40 iters x 32
#define N_FILT  16
#define REL_D   16
#define BATCH   32
#define NQ      512
#define KWAVE   1280      // GPAD / 4 waves
#define NIT     40        // KWAVE / 32

typedef __attribute__((ext_vector_type(8))) short bf16x8;
typedef __attribute__((ext_vector_type(4))) float f32x4;

static __device__ inline unsigned short f2bf(float x) {
    union { float f; unsigned int u; } v; v.f = x;
    unsigned int r = v.u + 0x7fffu + ((v.u >> 16) & 1u);   // RNE
    return (unsigned short)(r >> 16);
}
static __device__ inline float bfbits2f(unsigned int bits) {
    union { unsigned int u; float f; } v; v.u = bits; return v.f;
}
static __device__ inline void gload_lds16(const void* g, void* l) {
    __builtin_amdgcn_global_load_lds(
        (const __attribute__((address_space(1))) unsigned int*)g,
        (__attribute__((address_space(3))) unsigned int*)(unsigned int)(uintptr_t)l,
        16, 0, 0);
}
// unrank lexicographic 3-combination of 32
static __device__ inline void unrank3(int g, int& a, int& b, int& c) {
    int rem = g;
    for (a = 0; a < 30; a++) { int cnt = ((31 - a) * (30 - a)) >> 1; if (rem < cnt) break; rem -= cnt; }
    for (b = a + 1; b < 31; b++) { if (rem < 31 - b) break; rem -= 31 - b; }
    c = b + 1 + rem;
}

// ================= L1: normw (blocks 0..511) + pairconv (512..1663) ==============
__global__ __launch_bounds__(256) void k_front(const float* __restrict__ logits,
                                               const float* __restrict__ inputs,
                                               const float* __restrict__ filters,
                                               unsigned short* __restrict__ normw,
                                               unsigned short* __restrict__ D) {
    __shared__ __align__(16) char smem[11648];
    int t = threadIdx.x;
    int role = blockIdx.x;

    if (role < NQ) {
        // ---------- normw: softplus -> triple product -> softmax -> bf16, K-padded --
        float* sp  = (float*)smem;                            // 32 floats
        float* red = (float*)(smem + 128);                    // 4 floats
        unsigned short* wrow = (unsigned short*)(smem + 144); // 5120 u16
        int q = role;
        if (t < N_OBJ) {
            float x = logits[q * N_OBJ + t];
            sp[t] = (x > 15.f) ? x : log1pf(expf(x));
        }
        if (t < GPAD - G_TOTAL) wrow[G_TOTAL + t] = 0;        // zero the K-pad
        __syncthreads();

        int g0 = t * 20;
        int aa, bb, cc;
        unrank3(g0, aa, bb, cc);

        float w[20];
        float lmax = -1e30f;
#pragma unroll
        for (int k = 0; k < 20; k++) {
            float v = -1e30f;
            if (g0 + k < G_TOTAL) v = sp[aa] * sp[bb] * sp[cc];
            w[k] = v;
            lmax = fmaxf(lmax, v);
            cc++;
            if (cc >= 32) { bb++; cc = bb + 1; if (cc >= 32) { aa++; bb = aa + 1; cc = bb + 1; } }
        }
#pragma unroll
        for (int off = 32; off; off >>= 1) lmax = fmaxf(lmax, __shfl_down(lmax, off, 64));
        if ((t & 63) == 0) red[t >> 6] = lmax;
        __syncthreads();
        float wmax = fmaxf(fmaxf(red[0], red[1]), fmaxf(red[2], red[3]));

        float lsum = 0.f;
#pragma unroll
        for (int k = 0; k < 20; k++) {
            float e = (g0 + k < G_TOTAL) ? expf(w[k] - wmax) : 0.f;
            w[k] = e;
            lsum += e;
        }
#pragma unroll
        for (int off = 32; off; off >>= 1) lsum += __shfl_down(lsum, off, 64);
        __syncthreads();
        if ((t & 63) == 0) red[t >> 6] = lsum;
        __syncthreads();
        float inv = 1.f / (red[0] + red[1] + red[2] + red[3]);

#pragma unroll
        for (int k = 0; k < 20; k++)
            if (g0 + k < G_TOTAL) wrow[g0 + k] = f2bf(w[k] * inv);
        __syncthreads();
        // coalesced padded row write: 5120 u16 = 640 uint4
        uint4* dstrow = (uint4*)(normw + (size_t)q * GPAD);
        const uint4* srow = (const uint4*)wrow;
        for (int i = t; i < 640; i += 256) dstrow[i] = srow[i];
    } else {
        // ---------- pairconv: D[xy][p][b*16+f] = dot_d(inputs[b,x,y,:], filters[f,p,:])
        float* flt = (float*)smem;            // [f][p_pad] 16*180 floats
        int bid = role - NQ;                  // 0..1151
        int p = bid >> 7;                     // 0..8
        int xb = bid & 127;
        for (int i = t; i < 576; i += 256) {
            int i4 = i * 4;
            int f = i4 / 144;
            int r = i4 - f * 144;
            *(float4*)&flt[f * 180 + (r >> 4) * 20 + (r & 15)] = *(const float4*)(filters + i4);
        }
        __syncthreads();

        int row = xb * 256 + t;               // b*1024 + xy
        int b = row >> 10, xy = row & 1023;
        const float4* src = (const float4*)(inputs + (size_t)row * 16);
        float4 s0 = src[0], s1 = src[1], s2 = src[2], s3 = src[3];

        unsigned short outv[16];
        const float* fb = &flt[p * 20];
#pragma unroll
        for (int f = 0; f < 16; f++) {
            float4 f0 = *(const float4*)(fb + f * 180);
            float4 f1 = *(const float4*)(fb + f * 180 + 4);
            float4 f2 = *(const float4*)(fb + f * 180 + 8);
            float4 f3 = *(const float4*)(fb + f * 180 + 12);
            float d = s0.x * f0.x + s0.y * f0.y + s0.z * f0.z + s0.w * f0.w;
            d += s1.x * f1.x + s1.y * f1.y + s1.z * f1.z + s1.w * f1.w;
            d += s2.x * f2.x + s2.y * f2.y + s2.z * f2.z + s2.w * f2.w;
            d += s3.x * f3.x + s3.y * f3.y + s3.z * f3.z + s3.w * f3.w;
            outv[f] = f2bf(d);
        }
        uint4* dst = (uint4*)(D + ((size_t)(xy * 9 + p)) * 512 + b * 16);
        dst[0] = ((uint4*)outv)[0];
        dst[1] = ((uint4*)outv)[1];
    }
}

// ===== L2: gather 9 pairs -> relT[n][g]  (620 blocks, 8 g each) ===================
__global__ __launch_bounds__(256) void k_mid(const unsigned short* __restrict__ D,
                                             unsigned short* __restrict__ relT) {
    __shared__ int tri[8];
    int t = threadIdx.x;
    int g0 = blockIdx.x * 8;
    if (t < 8) {
        int a, b, c;
        unrank3(g0 + t, a, b, c);
        tri[t] = a | (b << 8) | (c << 16);
    }
    __syncthreads();

    float s0[8], s1[8];
#pragma unroll
    for (int g = 0; g < 8; g++) {
        int pk = tri[g];
        int xs[3] = { pk & 255, (pk >> 8) & 255, (pk >> 16) & 255 };
        float x0 = 0.f, x1 = 0.f;
#pragma unroll
        for (int i = 0; i < 3; i++)
#pragma unroll
            for (int j = 0; j < 3; j++) {
                int xy = xs[i] * 32 + xs[j];
                unsigned int v = *(const unsigned int*)(D + (size_t)(xy * 9 + i * 3 + j) * 512 + t * 2);
                x0 += bfbits2f(v << 16);
                x1 += bfbits2f(v & 0xffff0000u);
            }
        s0[g] = x0; s1[g] = x1;
    }
    unsigned int pack0[4], pack1[4];
#pragma unroll
    for (int k = 0; k < 4; k++) {
        pack0[k] = f2bf(s0[2 * k]) | ((unsigned int)f2bf(s0[2 * k + 1]) << 16);
        pack1[k] = f2bf(s1[2 * k]) | ((unsigned int)f2bf(s1[2 * k + 1]) << 16);
    }
    *(uint4*)(relT + (size_t)(2 * t) * GPAD + g0)     = *(uint4*)pack0;
    *(uint4*)(relT + (size_t)(2 * t + 1) * GPAD + g0) = *(uint4*)pack1;
}

// ====== L3: full-K GEMM, 32x32 tile/block, K split across 4 waves, no barriers ====
// XCD-swizzled tiles: each XCD's 32 blocks cover a 4q x 8n rectangle whose A+B
// panels (3.9 MB) fit its 4 MB L2 -> 16x panel reuse hits L2 not Infinity Cache.
// Per-wave private double-buffered LDS; vmcnt(4) ring keeps one stage in flight.
__global__ __launch_bounds__(256) void k_gemmf(const unsigned short* __restrict__ A,
                                               const unsigned short* __restrict__ Bm,
                                               float* __restrict__ out) {
    __shared__ __align__(16) char smem[32768];   // [wave][buf][A(2KB)|B(2KB)]
    int tid = threadIdx.x;
    int wave = tid >> 6, lane = tid & 63;
    int blk = blockIdx.x;
    int xcd = blk & 7, loc = blk >> 3;           // round-robin block->XCD
    int qt = (xcd & 3) * 4 + (loc & 3);          // 16 q-tiles
    int nt = (xcd >> 2) * 8 + (loc >> 2);        // 16 n-tiles
    int q0 = qt * 32, n0 = nt * 32;
    int row16 = lane & 15, quad = lane >> 4;

    // staging map: lane -> (srow = lane>>2 in 0..15, chunk slot lane&3), XOR swizzle
    int srow = lane >> 2;
    int schunk = (lane & 3) ^ ((srow >> 1) & 3);
    const unsigned short* gA = A  + (size_t)(q0 + srow) * GPAD + wave * KWAVE + schunk * 8;
    const unsigned short* gB = Bm + (size_t)(n0 + srow) * GPAD + wave * KWAVE + schunk * 8;
    char* lw = smem + wave * 8192;
    char* ld = lw + lane * 16;

    f32x4 acc[2][2] = {};
    int fslot = (quad ^ ((row16 >> 1) & 3)) * 16;

#define GSTAGE(itn, bufsel)                                   \
    {                                                         \
        char* dd_ = ld + (bufsel) * 4096;                     \
        int ko_ = (itn) * 32;                                 \
        gload_lds16(gA + ko_,             dd_);               \
        gload_lds16(gA + 16 * GPAD + ko_, dd_ + 1024);        \
        gload_lds16(gB + ko_,             dd_ + 2048);        \
        gload_lds16(gB + 16 * GPAD + ko_, dd_ + 3072);        \
    }

    GSTAGE(0, 0)
    GSTAGE(1, 1)
#pragma unroll 2
    for (int it = 0; it < NIT - 1; ++it) {
        int buf = it & 1;
        asm volatile("s_waitcnt vmcnt(4)" ::: "memory");   // buf `it` landed
        const char* fb = lw + buf * 4096;
        bf16x8 a0 = *(const bf16x8*)(fb + row16 * 64 + fslot);
        bf16x8 a1 = *(const bf16x8*)(fb + 1024 + row16 * 64 + fslot);
        bf16x8 b0 = *(const bf16x8*)(fb + 2048 + row16 * 64 + fslot);
        bf16x8 b1 = *(const bf16x8*)(fb + 3072 + row16 * 64 + fslot);
        asm volatile("s_waitcnt lgkmcnt(0)" ::: "memory"); // frags in regs
        if (it + 2 < NIT) GSTAGE(it + 2, buf)              // refill this buf
        acc[0][0] = __builtin_amdgcn_mfma_f32_16x16x32_bf16(a0, b0, acc[0][0], 0, 0, 0);
        acc[0][1] = __builtin_amdgcn_mfma_f32_16x16x32_bf16(a0, b1, acc[0][1], 0, 0, 0);
        acc[1][0] = __builtin_amdgcn_mfma_f32_16x16x32_bf16(a1, b0, acc[1][0], 0, 0, 0);
        acc[1][1] = __builtin_amdgcn_mfma_f32_16x16x32_bf16(a1, b1, acc[1][1], 0, 0, 0);
    }
    {   // final iteration: drain everything
        int buf = (NIT - 1) & 1;
        asm volatile("s_waitcnt vmcnt(0)" ::: "memory");
        const char* fb = lw + buf * 4096;
        bf16x8 a0 = *(const bf16x8*)(fb + row16 * 64 + fslot);
        bf16x8 a1 = *(const bf16x8*)(fb + 1024 + row16 * 64 + fslot);
        bf16x8 b0 = *(const bf16x8*)(fb + 2048 + row16 * 64 + fslot);
        bf16x8 b1 = *(const bf16x8*)(fb + 3072 + row16 * 64 + fslot);
        acc[0][0] = __builtin_amdgcn_mfma_f32_16x16x32_bf16(a0, b0, acc[0][0], 0, 0, 0);
        acc[0][1] = __builtin_amdgcn_mfma_f32_16x16x32_bf16(a0, b1, acc[0][1], 0, 0, 0);
        acc[1][0] = __builtin_amdgcn_mfma_f32_16x16x32_bf16(a1, b0, acc[1][0], 0, 0, 0);
        acc[1][1] = __builtin_amdgcn_mfma_f32_16x16x32_bf16(a1, b1, acc[1][1], 0, 0, 0);
    }
#undef GSTAGE

    // cross-wave K-reduction through LDS (reuse staging space)
    __syncthreads();
    float* red = (float*)smem;                 // 4 waves x 1024 f32 = 16 KB
#pragma unroll
    for (int mi = 0; mi < 2; mi++)
#pragma unroll
        for (int ni = 0; ni < 2; ni++)
#pragma unroll
            for (int r = 0; r < 4; r++)
                red[wave * 1024 + (mi * 16 + quad * 4 + r) * 32 + ni * 16 + row16] =
                    acc[mi][ni][r];
    __syncthreads();

    int e = tid * 4;                            // 4 consecutive elems per thread
    float4 s = *(const float4*)&red[e];
#pragma unroll
    for (int w = 1; w < 4; w++) {
        float4 v = *(const float4*)&red[w * 1024 + e];
        s.x += v.x; s.y += v.y; s.z += v.z; s.w += v.w;
    }
    int ql = e >> 5, nl = e & 31;
    int nn = n0 + nl;
    *(float4*)(out + (size_t)(nn >> 4) * (NQ * REL_D) + (q0 + ql) * 16 + (nn & 15)) = s;
}

extern "C" void kernel_launch(void* const* d_in, const int* in_sizes, int n_in,
                              void* d_out, int out_size, void* d_ws, size_t ws_size,
                              hipStream_t stream) {
    const float* inputs  = (const float*)d_in[0];   // (32,32,32,16)
    const float* logits  = (const float*)d_in[1];   // (512,32)
    const float* filters = (const float*)d_in[2];   // (16,3,3,16)
    float* out = (float*)d_out;                     // (32,512,16)

    char* ws = (char*)d_ws;
    unsigned short* normw = (unsigned short*)ws;                 //  5,242,880 B
    unsigned short* D     = (unsigned short*)(ws + 5242880);     //  9,437,184 B
    unsigned short* relT  = (unsigned short*)(ws + 14680064);    //  5,242,880 B

    k_front<<<NQ + 1152, 256, 0, stream>>>(logits, inputs, filters, normw, D);
    k_mid<<<G_TOTAL / 8, 256, 0, stream>>>(D, relT);
    k_gemmf<<<dim3(256), 256, 0, stream>>>(normw, relT, out);
}